// Round 17
// baseline (130.502 us; speedup 1.0000x reference)
//
#include <hip/hip_runtime.h>
#include <hip/hip_bf16.h>

// Gram reassociation, wide-chain form (no softmax in reference):
//   O_h = X_h Wq^T Wk G Wv^T,  G = X_h^T X_h,  Mt = Wk^T Wq
//   Q' = gemm_bt(X_h, Mt) = X M ;  R = gemm_bt(Q', G) = Q' G (G symmetric);
//   O  = gemm_bt(R, Wv) -> f32 out.
// R16: replace the latency-bound small-GEMM chain (Yt,Ut + 2 reduces,
// ~24us for 8.6GF) with three wide 4096-row GEMMs (1024 blocks each,
// single-occupancy-round). 5 launches: prep -> B1{G-tri || Mt} ->
// {Q' || redG merged} -> R -> O. Core: BK=64 + T2 XOR swizzle (rule #21:
// pre-swizzled global src + same XOR on LDS read), R11 fence discipline,
// LDS-staged coalesced epilogue. All proven in R15.

using bf16 = __hip_bfloat16;
typedef __attribute__((ext_vector_type(8))) __bf16 bf16x8;
typedef __attribute__((ext_vector_type(8))) unsigned short u16x8;
typedef __attribute__((ext_vector_type(4))) float f32x4;

#define M1 (1024 * 1024)

struct GB {   // per-z batch (blockIdx.z-indexed, wave-uniform)
    const bf16* A[8];
    const bf16* B[8];
    void*       C[8];
    int lda[8];
    int ldb[8];
};

__device__ __forceinline__ void gload_lds16(const void* g, void* l) {
    __builtin_amdgcn_global_load_lds(
        (const __attribute__((address_space(1))) void*)g,
        (__attribute__((address_space(3))) void*)l, 16, 0, 0);
}

__device__ __forceinline__ void waitv0() {
    asm volatile("s_waitcnt vmcnt(0)" ::: "memory");
}

// ---- shared GEMM core: C(+m0,n0 tile) = A B^T over Ksub, bt-form, BK=64 ----
template<int BM_, int BN_, typename OUT_T>
__device__ __forceinline__ void gemm_core(
    const bf16* __restrict__ A, int lda,
    const bf16* __restrict__ B, int ldb,
    OUT_T* __restrict__ C, int ldc,
    int m0, int n0, int Ksub,
    unsigned short* smem, int tid)
{
    constexpr int BK = 64;
    unsigned short* As = smem;             // BM_*64 shorts
    unsigned short* Bs = smem + BM_ * BK;  // BN_*64 shorts

    constexpr int MI = BM_ / 32;
    constexpr int NI = BN_ / 32;

    const int lane = tid & 63;
    const int wave = tid >> 6;
    const int wm   = wave >> 1;
    const int wn   = wave & 1;
    const int fr = lane & 15;
    const int kg = lane >> 4;

    const int srow  = tid >> 3;            // 0..31
    const int scol  = (tid & 7) * 8;       // 0..56 (16B granules)
    const int scolg = scol ^ ((srow & 7) << 3);   // pre-swizzled global col

    f32x4 acc[MI][NI];
    #pragma unroll
    for (int i = 0; i < MI; ++i)
        #pragma unroll
        for (int j = 0; j < NI; ++j)
            acc[i][j] = {0.f, 0.f, 0.f, 0.f};

    const int niter = Ksub >> 6;
    for (int it = 0; it < niter; ++it) {
        const int kt = it << 6;
        #pragma unroll
        for (int r = 0; r < BM_ / 32; ++r)
            gload_lds16(A + (size_t)(m0 + r * 32 + srow) * lda + (kt + scolg),
                        &As[(r * 32 + srow) * BK + scol]);
        #pragma unroll
        for (int r = 0; r < BN_ / 32; ++r)
            gload_lds16(B + (size_t)(n0 + r * 32 + srow) * ldb + (kt + scolg),
                        &Bs[(r * 32 + srow) * BK + scol]);
        waitv0();
        __builtin_amdgcn_s_barrier();             // buf filled, all waves
        __builtin_amdgcn_sched_barrier(0);

        #pragma unroll
        for (int kk = 0; kk < 2; ++kk) {
            bf16x8 af[MI], bfg[NI];
            #pragma unroll
            for (int mi = 0; mi < MI; ++mi) {
                const int row = wm * (BM_ / 2) + mi * 16 + fr;
                const int c = (kk * 32 + kg * 8) ^ ((row & 7) << 3);
                af[mi] = *(const bf16x8*)&As[row * BK + c];
            }
            #pragma unroll
            for (int ni = 0; ni < NI; ++ni) {
                const int row = wn * (BN_ / 2) + ni * 16 + fr;
                const int c = (kk * 32 + kg * 8) ^ ((row & 7) << 3);
                bfg[ni] = *(const bf16x8*)&Bs[row * BK + c];
            }
            #pragma unroll
            for (int mi = 0; mi < MI; ++mi)
                #pragma unroll
                for (int ni = 0; ni < NI; ++ni)
                    acc[mi][ni] = __builtin_amdgcn_mfma_f32_16x16x32_bf16(
                        af[mi], bfg[ni], acc[mi][ni], 0, 0, 0);
        }

        __builtin_amdgcn_sched_barrier(0);        // reads done before...
        __builtin_amdgcn_s_barrier();             // ...anyone re-stages
        __builtin_amdgcn_sched_barrier(0);
    }

    // epilogue: acc -> LDS tile -> coalesced stores
    // C/D layout: col = lane&15, row = (lane>>4)*4 + j  [m89-verified]
    if constexpr (sizeof(OUT_T) == 2) {
        #pragma unroll
        for (int mi = 0; mi < MI; ++mi)
            #pragma unroll
            for (int ni = 0; ni < NI; ++ni) {
                const int c = wn * (BN_ / 2) + ni * 16 + fr;
                #pragma unroll
                for (int j = 0; j < 4; ++j) {
                    const int r = wm * (BM_ / 2) + mi * 16 + kg * 4 + j;
                    bf16 h = __float2bfloat16(acc[mi][ni][j]);
                    smem[r * BN_ + c] = *(unsigned short*)&h;
                }
            }
        __syncthreads();
        constexpr int V = (BM_ * BN_) / 2048;
        #pragma unroll
        for (int v = 0; v < V; ++v) {
            const int off = v * 2048 + tid * 8;
            const int r = off / BN_;
            const int c = off % BN_;
            *(u16x8*)((unsigned short*)C + (size_t)(m0 + r) * ldc + n0 + c) =
                *(const u16x8*)&smem[off];
        }
    } else {
        float* fs = (float*)smem;
        #pragma unroll
        for (int mi = 0; mi < MI; ++mi)
            #pragma unroll
            for (int ni = 0; ni < NI; ++ni) {
                const int c = wn * (BN_ / 2) + ni * 16 + fr;
                #pragma unroll
                for (int j = 0; j < 4; ++j) {
                    const int r = wm * (BM_ / 2) + mi * 16 + kg * 4 + j;
                    fs[r * BN_ + c] = acc[mi][ni][j];
                }
            }
        __syncthreads();
        constexpr int V = (BM_ * BN_) / 1024;
        #pragma unroll
        for (int v = 0; v < V; ++v) {
            const int off = v * 1024 + tid * 4;
            const int r = off / BN_;
            const int c = off % BN_;
            *(float4*)((float*)C + (size_t)(m0 + r) * ldc + n0 + c) =
                *(const float4*)&fs[off];
        }
    }
}

// ---- generic batched GEMM (R, O) ----
template<int BM_, int BN_, typename OUT_T>
__global__ __launch_bounds__(256, 4)
void gemm_bt_pa(GB g, int Ksub, int ldc)
{
    constexpr int STAGE_SH = (BM_ + BN_) * 64;
    constexpr int EPI_SH   = BM_ * BN_ * (int)sizeof(OUT_T) / 2;
    constexpr int SMEM_SH  = STAGE_SH > EPI_SH ? STAGE_SH : EPI_SH;
    __shared__ __align__(16) unsigned short smem[SMEM_SH];

    const int gx = gridDim.x, gy = gridDim.y;
    const int nwg = gx * gy * gridDim.z;
    const int orig = blockIdx.x + gx * (blockIdx.y + gy * blockIdx.z);
    const int cpx = nwg >> 3;
    const int wg = (orig & 7) * cpx + (orig >> 3);
    const int bx = wg % gx;
    const int by = (wg / gx) % gy;
    const int bz = wg / (gx * gy);

    gemm_core<BM_, BN_, OUT_T>(g.A[bz], g.lda[bz], g.B[bz], g.ldb[bz],
                               (OUT_T*)g.C[bz], ldc,
                               by * BM_, bx * BN_, Ksub,
                               smem, threadIdx.x);
}

// ---- B1: G upper-tri (576 blk, splitK8, 8 iters) || Mt full-K (128 blk) ----
struct B1Args {
    const bf16* xt;      // [2048][4096]
    const bf16* wdst;    // WqT0,WqT1,WkT0,WkT1,Wv0,Wv1
    bf16* Gp;            // compact partials [16 z][36 tiles][128*128]
    bf16* Mtb;           // [2][1024*1024] Mt = Wk^T Wq (no reduce)
};

__global__ __launch_bounds__(256, 4)
void b1_kernel(B1Args a)
{
    __shared__ __align__(16) unsigned short smem[16384];   // 32 KB

    const int nwg = 704;                     // 576 + 128
    const int orig = blockIdx.x;
    const int cpx = nwg >> 3;                // 88
    const int wg = (orig & 7) * cpx + (orig >> 3);

    if (wg < 576) {
        const int z = wg / 36;               // 0..15
        const int tile = wg - z * 36;
        const int h = z >> 3, s = z & 7;
        int ti = 0, rem = tile;
        while (rem >= 8 - ti) { rem -= 8 - ti; ++ti; }
        const int tj = ti + rem;
        const bf16* A = a.xt + (size_t)(h * 1024 + ti * 128) * 4096 + s * 512;
        const bf16* B = a.xt + (size_t)(h * 1024 + tj * 128) * 4096 + s * 512;
        bf16* C = a.Gp + ((size_t)z * 36 + tile) * 16384;
        gemm_core<128, 128, bf16>(A, 4096, B, 4096, C, 128, 0, 0, 512,
                                  smem, threadIdx.x);
    } else {
        const int idx = wg - 576;            // 0..127
        const int h = idx >> 6;
        const int tile = idx & 63;
        const int m0 = (tile >> 3) * 128;
        const int n0 = (tile & 7) * 128;
        // Mt = gemm_bt(WkT, WqT) = Wk^T Wq, full K=1024 (downstream uses
        // Q' = gemm_bt(xb, Mt) = X Wq^T Wk — orientation re-derived, R12 lesson)
        const bf16* A = a.wdst + (size_t)(2 + h) * M1;   // WkT_h
        const bf16* B = a.wdst + (size_t)h * M1;         // WqT_h
        bf16* C = a.Mtb + (size_t)h * M1;
        gemm_core<128, 128, bf16>(A, 1024, B, 1024, C, 1024, m0, n0, 1024,
                                  smem, threadIdx.x);
    }
}

// ---- merged: Q' = gemm_bt(xb, Mt) (1024 blk) || redG+mirror (576 blk) ----
struct QRArgs {
    const bf16* xb;              // 4096x2048
    const bf16* Mtb;             // [2][1M]
    const unsigned short* Gp;    // compact partials (d_out)
    bf16* Qp;                    // [2][4M]
    unsigned short* Gd;          // full mirrored G [2][1M]
};

__global__ __launch_bounds__(256, 4)
void q_redg_kernel(QRArgs a)
{
    __shared__ __align__(16) unsigned short smem[12288];   // 24 KB (128+64)*64

    const int nwg = 1600;
    const int orig = blockIdx.x;
    const int cpx = nwg >> 3;                // 200
    const int wg = (orig & 7) * cpx + (orig >> 3);

    if (wg < 1024) {
        const int bx = wg & 15;              // 16 n-tiles (64 cols)
        const int by = (wg >> 4) & 31;       // 32 m-tiles (128 rows)
        const int h  = wg >> 9;
        gemm_core<128, 64, bf16>(a.xb + h * 1024, 2048,
                                 a.Mtb + (size_t)h * M1, 1024,
                                 a.Qp + (size_t)h * 4 * M1, 1024,
                                 by * 128, bx * 64, 1024,
                                 smem, threadIdx.x);
    } else {
        const int b = wg - 1024;             // 0..575
        const int t = threadIdx.x;
        const int h    = b / 288;
        const int rem  = b - h * 288;
        const int tile = rem >> 3;
        const int blk  = rem & 7;
        int ti = 0, trem = tile;
        while (trem >= 8 - ti) { trem -= 8 - ti; ++ti; }
        const int tj = ti + trem;

        const int e  = blk * 2048 + t * 8;
        const int r  = e >> 7;
        const int c0 = e & 127;

        float acc[8] = {0, 0, 0, 0, 0, 0, 0, 0};
        for (int s = 0; s < 8; ++s) {
            u16x8 v = *(const u16x8*)(a.Gp + ((size_t)(h * 8 + s) * 36 + tile) * 16384 + e);
            #pragma unroll
            for (int j = 0; j < 8; ++j)
                acc[j] += __uint_as_float(((unsigned)v[j]) << 16);
        }
        u16x8 o;
        #pragma unroll
        for (int j = 0; j < 8; ++j) {
            bf16 hh = __float2bfloat16(acc[j]);
            o[j] = *(unsigned short*)&hh;
        }
        unsigned short* G = a.Gd + (size_t)h * M1;
        *(u16x8*)(G + (size_t)(ti * 128 + r) * 1024 + tj * 128 + c0) = o;
        if (ti != tj) {
            #pragma unroll
            for (int j = 0; j < 8; ++j)
                G[(size_t)(tj * 128 + c0 + j) * 1024 + ti * 128 + r] = o[j];
        }
    }
}

// ---------------- prep: casts + transposes ----------------

__device__ __forceinline__ ushort4 cvt4(float4 v) {
    ushort4 o; bf16 h;
    h = __float2bfloat16(v.x); o.x = *(unsigned short*)&h;
    h = __float2bfloat16(v.y); o.y = *(unsigned short*)&h;
    h = __float2bfloat16(v.z); o.z = *(unsigned short*)&h;
    h = __float2bfloat16(v.w); o.w = *(unsigned short*)&h;
    return o;
}

struct PrepArgs {
    const float* x;
    const float* w[4];    // Wq1, Wq2, Wk1, Wk2 (to transpose)
    const float* wv[2];   // Wv1, Wv2 (straight)
    bf16* xb;
    bf16* xt;
    bf16* wdst;
};

__device__ void xpose64(const float* __restrict__ src, int ldsrc,
                        int r0, int c0,
                        bf16* __restrict__ dstS, int ldS,
                        bf16* __restrict__ dstT, int ldT,
                        float (*tile)[65], int t)
{
    const int tr  = t >> 4;
    const int tc4 = (t & 15) * 4;
    #pragma unroll
    for (int ph = 0; ph < 4; ++ph) {
        const int row = ph * 16 + tr;
        float4 v = *(const float4*)(src + (size_t)(r0 + row) * ldsrc + c0 + tc4);
        tile[row][tc4 + 0] = v.x;
        tile[row][tc4 + 1] = v.y;
        tile[row][tc4 + 2] = v.z;
        tile[row][tc4 + 3] = v.w;
        if (dstS)
            *(ushort4*)((unsigned short*)dstS + (size_t)(r0 + row) * ldS + c0 + tc4) = cvt4(v);
    }
    __syncthreads();
    #pragma unroll
    for (int ph = 0; ph < 4; ++ph) {
        const int crow = ph * 16 + tr;
        float4 v = {tile[tc4 + 0][crow], tile[tc4 + 1][crow],
                    tile[tc4 + 2][crow], tile[tc4 + 3][crow]};
        *(ushort4*)((unsigned short*)dstT + (size_t)(c0 + crow) * ldT + r0 + tc4) = cvt4(v);
    }
}

__global__ void prep(PrepArgs p)
{
    __shared__ float tile[64][65];
    const int b = blockIdx.x;
    const int t = threadIdx.x;

    if (b < 2048) {
        const int n0 = (b & 63) * 64;
        const int c0 = (b >> 6) * 64;
        xpose64(p.x, 2048, n0, c0, p.xb, 2048, p.xt, 4096, tile, t);
    } else if (b < 3072) {
        const int i = b - 2048;
        const int mat = i >> 8;
        const int tl  = i & 255;
        const int r0 = (tl & 15) * 64;
        const int c0 = (tl >> 4) * 64;
        xpose64(p.w[mat], 1024, r0, c0, nullptr, 0,
                p.wdst + (size_t)mat * M1, 1024, tile, t);
    } else {
        const int i = b - 3072;
        const int mat = i >> 9;
        const int blk = i & 511;
        const size_t off = (size_t)blk * 2048 + t * 8;
        float4 v0 = *(const float4*)(p.wv[mat] + off);
        float4 v1 = *(const float4*)(p.wv[mat] + off + 4);
        unsigned short* d = (unsigned short*)p.wdst + (size_t)(4 + mat) * M1 + off;
        *(ushort4*)d       = cvt4(v0);
        *(ushort4*)(d + 4) = cvt4(v1);
    }
}

// ---------------- driver ----------------

extern "C" void kernel_launch(void* const* d_in, const int* in_sizes, int n_in,
                              void* d_out, int out_size, void* d_ws, size_t ws_size,
                              hipStream_t stream)
{
    // ws layout (bf16 elems): 42M elems = 84 MB (== R1-proven footprint)
    bf16* xb   = (bf16*)d_ws;                  // 8M elems
    bf16* xt   = xb + 8 * M1;                  // 8M
    bf16* wdst = xt + 8 * M1;                  // 6M
    bf16* Mtb  = wdst + 6 * M1;                // 2M
    bf16* Gb   = Mtb + 2 * M1;                 // 2M
    bf16* Qp   = Gb + 2 * M1;                  // 8M
    bf16* Rb   = Qp + 8 * M1;                  // 8M

    bf16* scr = (bf16*)d_out;                  // G partials until redG done

    PrepArgs pa;
    pa.x = (const float*)d_in[0];
    pa.w[0] = (const float*)d_in[1];  pa.w[1] = (const float*)d_in[2];
    pa.w[2] = (const float*)d_in[3];  pa.w[3] = (const float*)d_in[4];
    pa.wv[0] = (const float*)d_in[5]; pa.wv[1] = (const float*)d_in[6];
    pa.xb = xb; pa.xt = xt; pa.wdst = wdst;
    prep<<<4096, 256, 0, stream>>>(pa);

    // B1: G upper-tri (compact partials in scr) || Mt full-K (direct to Mtb)
    B1Args b1;
    b1.xt = xt; b1.wdst = wdst; b1.Gp = scr; b1.Mtb = Mtb;
    b1_kernel<<<704, 256, 0, stream>>>(b1);

    // merged: Q' = X M (1024 blk) || redG reduce+mirror (576 blk)
    QRArgs qr;
    qr.xb = xb; qr.Mtb = Mtb; qr.Gp = (const unsigned short*)scr;
    qr.Qp = Qp; qr.Gd = (unsigned short*)Gb;
    q_redg_kernel<<<1600, 256, 0, stream>>>(qr);

    GB g;

    // R = gemm_bt(Q', G) = Q' G (G symmetric), 128x64 tiles, 1024 blocks
    for (int z = 0; z < 2; ++z) {
        g.A[z] = Qp + (size_t)z * 4 * M1;  g.lda[z] = 1024;
        g.B[z] = Gb + (size_t)z * M1;      g.ldb[z] = 1024;
        g.C[z] = Rb + (size_t)z * 4 * M1;
    }
    gemm_bt_pa<128, 64, bf16><<<dim3(16, 32, 2), 256, 0, stream>>>(g, 1024, 1024);

    // O = gemm_bt(R, Wv) -> f32 out[:, h*1024:], 128x64 tiles, 1024 blocks
    for (int z = 0; z < 2; ++z) {
        g.A[z] = Rb + (size_t)z * 4 * M1;           g.lda[z] = 1024;
        g.B[z] = wdst + (size_t)(4 + z) * M1;       g.ldb[z] = 1024;
        g.C[z] = (float*)d_out + (size_t)z * 1024;
    }
    gemm_bt_pa<128, 64, float><<<dim3(16, 32, 2), 256, 0, stream>>>(g, 1024, 2048);
}

// Round 18
// 113.499 us; speedup vs baseline: 1.1498x; 1.1498x over previous
//
#include <hip/hip_runtime.h>
#include <hip/hip_bf16.h>

// Gram reassociation (no softmax in reference):
//   O_h = X_h * U_h,  U_h = M G Wv^T,  M = Wq^T Wk,  G = X_h^T X_h
// DAG (R15 = FLOP-minimal, proven 115.3us; R16/17 wide-chain regressed):
//   prep -> B1{G-tri splitK8 || M splitK2, ALL 8-iter} -> redGM (reduce G
//   compact partials + mirror; reduce M) -> Yt=M G (splitK4) -> red4 ->
//   Ut=gemm_bt(Wv,Yt) (splitK4) -> red4 -> O=gemm_bt(X,Ut) -> f32 out.
// R18 change vs R15: M back to splitK2 inside B1 (R13 structure) so B1's
// blocks are UNIFORMLY 8 iters — R15's full-K M branch (16 iters) was B1's
// critical path (launch = max over branches). M-reduce merged into redGM.
// Core: BK=64 + T2 XOR swizzle (rule #21), R11 fence discipline, LDS-staged
// coalesced epilogue — all proven.

using bf16 = __hip_bfloat16;
typedef __attribute__((ext_vector_type(8))) __bf16 bf16x8;
typedef __attribute__((ext_vector_type(8))) unsigned short u16x8;
typedef __attribute__((ext_vector_type(4))) float f32x4;

#define M1 (1024 * 1024)

struct GB {   // per-z batch (blockIdx.z-indexed, wave-uniform)
    const bf16* A[8];
    const bf16* B[8];
    void*       C[8];
    int lda[8];
    int ldb[8];
};

__device__ __forceinline__ void gload_lds16(const void* g, void* l) {
    __builtin_amdgcn_global_load_lds(
        (const __attribute__((address_space(1))) void*)g,
        (__attribute__((address_space(3))) void*)l, 16, 0, 0);
}

__device__ __forceinline__ void waitv0() {
    asm volatile("s_waitcnt vmcnt(0)" ::: "memory");
}

// ---- shared GEMM core: C(+m0,n0 tile) = A B^T over Ksub, bt-form, BK=64 ----
template<int BM_, int BN_, typename OUT_T>
__device__ __forceinline__ void gemm_core(
    const bf16* __restrict__ A, int lda,
    const bf16* __restrict__ B, int ldb,
    OUT_T* __restrict__ C, int ldc,
    int m0, int n0, int Ksub,
    unsigned short* smem, int tid)
{
    constexpr int BK = 64;
    unsigned short* As = smem;             // BM_*64 shorts
    unsigned short* Bs = smem + BM_ * BK;  // BN_*64 shorts

    constexpr int MI = BM_ / 32;
    constexpr int NI = BN_ / 32;

    const int lane = tid & 63;
    const int wave = tid >> 6;
    const int wm   = wave >> 1;
    const int wn   = wave & 1;
    const int fr = lane & 15;
    const int kg = lane >> 4;

    const int srow  = tid >> 3;            // 0..31
    const int scol  = (tid & 7) * 8;       // 0..56 (16B granules)
    const int scolg = scol ^ ((srow & 7) << 3);   // pre-swizzled global col

    f32x4 acc[MI][NI];
    #pragma unroll
    for (int i = 0; i < MI; ++i)
        #pragma unroll
        for (int j = 0; j < NI; ++j)
            acc[i][j] = {0.f, 0.f, 0.f, 0.f};

    const int niter = Ksub >> 6;
    for (int it = 0; it < niter; ++it) {
        const int kt = it << 6;
        #pragma unroll
        for (int r = 0; r < BM_ / 32; ++r)
            gload_lds16(A + (size_t)(m0 + r * 32 + srow) * lda + (kt + scolg),
                        &As[(r * 32 + srow) * BK + scol]);
        #pragma unroll
        for (int r = 0; r < BN_ / 32; ++r)
            gload_lds16(B + (size_t)(n0 + r * 32 + srow) * ldb + (kt + scolg),
                        &Bs[(r * 32 + srow) * BK + scol]);
        waitv0();
        __builtin_amdgcn_s_barrier();             // buf filled, all waves
        __builtin_amdgcn_sched_barrier(0);

        #pragma unroll
        for (int kk = 0; kk < 2; ++kk) {
            bf16x8 af[MI], bfg[NI];
            #pragma unroll
            for (int mi = 0; mi < MI; ++mi) {
                const int row = wm * (BM_ / 2) + mi * 16 + fr;
                const int c = (kk * 32 + kg * 8) ^ ((row & 7) << 3);
                af[mi] = *(const bf16x8*)&As[row * BK + c];
            }
            #pragma unroll
            for (int ni = 0; ni < NI; ++ni) {
                const int row = wn * (BN_ / 2) + ni * 16 + fr;
                const int c = (kk * 32 + kg * 8) ^ ((row & 7) << 3);
                bfg[ni] = *(const bf16x8*)&Bs[row * BK + c];
            }
            #pragma unroll
            for (int mi = 0; mi < MI; ++mi)
                #pragma unroll
                for (int ni = 0; ni < NI; ++ni)
                    acc[mi][ni] = __builtin_amdgcn_mfma_f32_16x16x32_bf16(
                        af[mi], bfg[ni], acc[mi][ni], 0, 0, 0);
        }

        __builtin_amdgcn_sched_barrier(0);        // reads done before...
        __builtin_amdgcn_s_barrier();             // ...anyone re-stages
        __builtin_amdgcn_sched_barrier(0);
    }

    // epilogue: acc -> LDS tile -> coalesced stores
    // C/D layout: col = lane&15, row = (lane>>4)*4 + j  [m89-verified]
    if constexpr (sizeof(OUT_T) == 2) {
        #pragma unroll
        for (int mi = 0; mi < MI; ++mi)
            #pragma unroll
            for (int ni = 0; ni < NI; ++ni) {
                const int c = wn * (BN_ / 2) + ni * 16 + fr;
                #pragma unroll
                for (int j = 0; j < 4; ++j) {
                    const int r = wm * (BM_ / 2) + mi * 16 + kg * 4 + j;
                    bf16 h = __float2bfloat16(acc[mi][ni][j]);
                    smem[r * BN_ + c] = *(unsigned short*)&h;
                }
            }
        __syncthreads();
        constexpr int V = (BM_ * BN_) / 2048;
        #pragma unroll
        for (int v = 0; v < V; ++v) {
            const int off = v * 2048 + tid * 8;
            const int r = off / BN_;
            const int c = off % BN_;
            *(u16x8*)((unsigned short*)C + (size_t)(m0 + r) * ldc + n0 + c) =
                *(const u16x8*)&smem[off];
        }
    } else {
        float* fs = (float*)smem;
        #pragma unroll
        for (int mi = 0; mi < MI; ++mi)
            #pragma unroll
            for (int ni = 0; ni < NI; ++ni) {
                const int c = wn * (BN_ / 2) + ni * 16 + fr;
                #pragma unroll
                for (int j = 0; j < 4; ++j) {
                    const int r = wm * (BM_ / 2) + mi * 16 + kg * 4 + j;
                    fs[r * BN_ + c] = acc[mi][ni][j];
                }
            }
        __syncthreads();
        constexpr int V = (BM_ * BN_) / 1024;
        #pragma unroll
        for (int v = 0; v < V; ++v) {
            const int off = v * 1024 + tid * 4;
            const int r = off / BN_;
            const int c = off % BN_;
            *(float4*)((float*)C + (size_t)(m0 + r) * ldc + n0 + c) =
                *(const float4*)&fs[off];
        }
    }
}

// ---- generic batched GEMM (L4, L6, O) ----
template<int BM_, int BN_, typename OUT_T>
__global__ __launch_bounds__(256, 4)
void gemm_bt_pa(GB g, int Ksub, int ldc)
{
    constexpr int STAGE_SH = (BM_ + BN_) * 64;
    constexpr int EPI_SH   = BM_ * BN_ * (int)sizeof(OUT_T) / 2;
    constexpr int SMEM_SH  = STAGE_SH > EPI_SH ? STAGE_SH : EPI_SH;
    __shared__ __align__(16) unsigned short smem[SMEM_SH];

    const int gx = gridDim.x, gy = gridDim.y;
    const int nwg = gx * gy * gridDim.z;
    const int orig = blockIdx.x + gx * (blockIdx.y + gy * blockIdx.z);
    const int cpx = nwg >> 3;
    const int wg = (orig & 7) * cpx + (orig >> 3);
    const int bx = wg % gx;
    const int by = (wg / gx) % gy;
    const int bz = wg / (gx * gy);

    gemm_core<BM_, BN_, OUT_T>(g.A[bz], g.lda[bz], g.B[bz], g.ldb[bz],
                               (OUT_T*)g.C[bz], ldc,
                               by * BM_, bx * BN_, Ksub,
                               smem, threadIdx.x);
}

// ---- B1: G upper-tri (576 blk, splitK8) || M splitK2 (256 blk) — all 8-iter ----
struct B1Args {
    const bf16* xt;      // [2048][4096]
    const bf16* wdst;    // WqT0,WqT1,WkT0,WkT1,Wv0,Wv1
    bf16* Gp;            // compact G partials [16 z][36 tiles][128*128] (d_out)
    bf16* Mp;            // M partials [4 = h*2+s][1024*1024] (ws)
};

__global__ __launch_bounds__(256, 4)
void b1_kernel(B1Args a)
{
    __shared__ __align__(16) unsigned short smem[16384];   // 32 KB

    const int nwg = 832;                     // 576 + 256
    const int orig = blockIdx.x;
    const int cpx = nwg >> 3;                // 104
    const int wg = (orig & 7) * cpx + (orig >> 3);

    if (wg < 576) {
        const int z = wg / 36;               // 0..15
        const int tile = wg - z * 36;
        const int h = z >> 3, s = z & 7;
        int ti = 0, rem = tile;
        while (rem >= 8 - ti) { rem -= 8 - ti; ++ti; }
        const int tj = ti + rem;
        const bf16* A = a.xt + (size_t)(h * 1024 + ti * 128) * 4096 + s * 512;
        const bf16* B = a.xt + (size_t)(h * 1024 + tj * 128) * 4096 + s * 512;
        bf16* C = a.Gp + ((size_t)z * 36 + tile) * 16384;
        gemm_core<128, 128, bf16>(A, 4096, B, 4096, C, 128, 0, 0, 512,
                                  smem, threadIdx.x);
    } else {
        const int idx = wg - 576;            // 0..255
        const int combo = idx >> 6;          // 0..3 = h*2+s
        const int h = combo >> 1, s = combo & 1;
        const int tile = idx & 63;
        const int m0 = (tile >> 3) * 128;
        const int n0 = (tile & 7) * 128;
        // M = gemm_bt(WqT, WkT) = Wq^T Wk  (R13-proven operand order)
        const bf16* A = a.wdst + (size_t)h * M1 + s * 512;         // WqT_h
        const bf16* B = a.wdst + (size_t)(2 + h) * M1 + s * 512;   // WkT_h
        bf16* C = a.Mp + (size_t)combo * M1;
        gemm_core<128, 128, bf16>(A, 1024, B, 1024, C, 1024, m0, n0, 512,
                                  smem, threadIdx.x);
    }
}

// ---------------- prep: casts + transposes ----------------

__device__ __forceinline__ ushort4 cvt4(float4 v) {
    ushort4 o; bf16 h;
    h = __float2bfloat16(v.x); o.x = *(unsigned short*)&h;
    h = __float2bfloat16(v.y); o.y = *(unsigned short*)&h;
    h = __float2bfloat16(v.z); o.z = *(unsigned short*)&h;
    h = __float2bfloat16(v.w); o.w = *(unsigned short*)&h;
    return o;
}

struct PrepArgs {
    const float* x;
    const float* w[4];    // Wq1, Wq2, Wk1, Wk2 (to transpose)
    const float* wv[2];   // Wv1, Wv2 (straight)
    bf16* xb;
    bf16* xt;
    bf16* wdst;
};

__device__ void xpose64(const float* __restrict__ src, int ldsrc,
                        int r0, int c0,
                        bf16* __restrict__ dstS, int ldS,
                        bf16* __restrict__ dstT, int ldT,
                        float (*tile)[65], int t)
{
    const int tr  = t >> 4;
    const int tc4 = (t & 15) * 4;
    #pragma unroll
    for (int ph = 0; ph < 4; ++ph) {
        const int row = ph * 16 + tr;
        float4 v = *(const float4*)(src + (size_t)(r0 + row) * ldsrc + c0 + tc4);
        tile[row][tc4 + 0] = v.x;
        tile[row][tc4 + 1] = v.y;
        tile[row][tc4 + 2] = v.z;
        tile[row][tc4 + 3] = v.w;
        if (dstS)
            *(ushort4*)((unsigned short*)dstS + (size_t)(r0 + row) * ldS + c0 + tc4) = cvt4(v);
    }
    __syncthreads();
    #pragma unroll
    for (int ph = 0; ph < 4; ++ph) {
        const int crow = ph * 16 + tr;
        float4 v = {tile[tc4 + 0][crow], tile[tc4 + 1][crow],
                    tile[tc4 + 2][crow], tile[tc4 + 3][crow]};
        *(ushort4*)((unsigned short*)dstT + (size_t)(c0 + crow) * ldT + r0 + tc4) = cvt4(v);
    }
}

__global__ void prep(PrepArgs p)
{
    __shared__ float tile[64][65];
    const int b = blockIdx.x;
    const int t = threadIdx.x;

    if (b < 2048) {
        const int n0 = (b & 63) * 64;
        const int c0 = (b >> 6) * 64;
        xpose64(p.x, 2048, n0, c0, p.xb, 2048, p.xt, 4096, tile, t);
    } else if (b < 3072) {
        const int i = b - 2048;
        const int mat = i >> 8;
        const int tl  = i & 255;
        const int r0 = (tl & 15) * 64;
        const int c0 = (tl >> 4) * 64;
        xpose64(p.w[mat], 1024, r0, c0, nullptr, 0,
                p.wdst + (size_t)mat * M1, 1024, tile, t);
    } else {
        const int i = b - 3072;
        const int mat = i >> 9;
        const int blk = i & 511;
        const size_t off = (size_t)blk * 2048 + t * 8;
        float4 v0 = *(const float4*)(p.wv[mat] + off);
        float4 v1 = *(const float4*)(p.wv[mat] + off + 4);
        unsigned short* d = (unsigned short*)p.wdst + (size_t)(4 + mat) * M1 + off;
        *(ushort4*)d       = cvt4(v0);
        *(ushort4*)(d + 4) = cvt4(v1);
    }
}

// ---------------- reduces ----------------

__device__ __forceinline__ void reduce_slices(const unsigned short* src,
                                              unsigned short* dst,
                                              int h, int r, int nslice)
{
    float acc[8] = {0, 0, 0, 0, 0, 0, 0, 0};
    for (int s = 0; s < nslice; ++s) {
        u16x8 v = *(const u16x8*)(src + ((size_t)(h * nslice + s) << 20) + r);
        #pragma unroll
        for (int j = 0; j < 8; ++j)
            acc[j] += __uint_as_float(((unsigned)v[j]) << 16);
    }
    u16x8 o;
    #pragma unroll
    for (int j = 0; j < 8; ++j) {
        bf16 hh = __float2bfloat16(acc[j]);
        o[j] = *(unsigned short*)&hh;
    }
    *(u16x8*)(dst + ((size_t)h << 20) + r) = o;
}

// blocks 0..575: reduce compact G partials (8 slices) -> full mirrored G.
// blocks 576..1599: reduce M (2 slices).
__global__ void reduce_GM(const unsigned short* Gp, const unsigned short* Mp,
                          unsigned short* Gd, unsigned short* Md)
{
    const int b = blockIdx.x, t = threadIdx.x;
    if (b < 576) {
        const int h    = b / 288;
        const int rem  = b - h * 288;
        const int tile = rem >> 3;
        const int blk  = rem & 7;
        int ti = 0, trem = tile;
        while (trem >= 8 - ti) { trem -= 8 - ti; ++ti; }
        const int tj = ti + trem;

        const int e  = blk * 2048 + t * 8;
        const int r  = e >> 7;
        const int c0 = e & 127;

        float acc[8] = {0, 0, 0, 0, 0, 0, 0, 0};
        for (int s = 0; s < 8; ++s) {
            u16x8 v = *(const u16x8*)(Gp + ((size_t)(h * 8 + s) * 36 + tile) * 16384 + e);
            #pragma unroll
            for (int j = 0; j < 8; ++j)
                acc[j] += __uint_as_float(((unsigned)v[j]) << 16);
        }
        u16x8 o;
        #pragma unroll
        for (int j = 0; j < 8; ++j) {
            bf16 hh = __float2bfloat16(acc[j]);
            o[j] = *(unsigned short*)&hh;
        }
        unsigned short* G = Gd + (size_t)h * M1;
        *(u16x8*)(G + (size_t)(ti * 128 + r) * 1024 + tj * 128 + c0) = o;
        if (ti != tj) {
            #pragma unroll
            for (int j = 0; j < 8; ++j)
                G[(size_t)(tj * 128 + c0 + j) * 1024 + ti * 128 + r] = o[j];
        }
    } else {
        const int e = ((b - 576) * 256 + t) * 8;
        reduce_slices(Mp, Md, e >> 20, e & (M1 - 1), 2);
    }
}

__global__ void reduce_4(const unsigned short* Sp, unsigned short* Dd)
{
    const int e = (blockIdx.x * 256 + threadIdx.x) * 8;
    reduce_slices(Sp, Dd, e >> 20, e & (M1 - 1), 4);
}

// ---------------- driver ----------------

extern "C" void kernel_launch(void* const* d_in, const int* in_sizes, int n_in,
                              void* d_out, int out_size, void* d_ws, size_t ws_size,
                              hipStream_t stream)
{
    // ws layout (bf16 elems): 34M elems = 68 MB (R13-proven footprint)
    bf16* xb   = (bf16*)d_ws;                  // 8M elems
    bf16* xt   = xb + 8 * M1;                  // 8M
    bf16* wdst = xt + 8 * M1;                  // 6M
    bf16* Mp   = wdst + 6 * M1;                // 4M  (M splitK2 partials)
    bf16* Mb   = Mp + 4 * M1;                  // 2M
    bf16* Gb   = Mb + 2 * M1;                  // 2M
    bf16* Ytb  = Gb + 2 * M1;                  // 2M
    bf16* Utb  = Ytb + 2 * M1;                 // 2M

    bf16* scr = (bf16*)d_out;                  // 32 MB scratch until final O

    PrepArgs pa;
    pa.x = (const float*)d_in[0];
    pa.w[0] = (const float*)d_in[1];  pa.w[1] = (const float*)d_in[2];
    pa.w[2] = (const float*)d_in[3];  pa.w[3] = (const float*)d_in[4];
    pa.wv[0] = (const float*)d_in[5]; pa.wv[1] = (const float*)d_in[6];
    pa.xb = xb; pa.xt = xt; pa.wdst = wdst;
    prep<<<4096, 256, 0, stream>>>(pa);

    // B1: G upper-tri (compact partials in scr) || M splitK2 (partials in Mp)
    B1Args b1;
    b1.xt = xt; b1.wdst = wdst; b1.Gp = scr; b1.Mp = Mp;
    b1_kernel<<<832, 256, 0, stream>>>(b1);

    // redGM: 576 G-blocks (reduce+mirror) + 1024 M-blocks
    reduce_GM<<<1600, 256, 0, stream>>>((const unsigned short*)scr,
                                        (const unsigned short*)Mp,
                                        (unsigned short*)Gb, (unsigned short*)Mb);

    GB g;

    // L4: Yt = M G (split-K4, Ksub=256 -> 4 iters), 512 blocks
    for (int z = 0; z < 8; ++z) {
        const int h = z >> 2, s = z & 3;
        g.A[z] = Mb + (size_t)h * M1 + s * 256;  g.lda[z] = 1024;
        g.B[z] = Gb + (size_t)h * M1 + s * 256;  g.ldb[z] = 1024;
        g.C[z] = (bf16*)scr + (size_t)z * M1;
    }
    gemm_bt_pa<128, 128, bf16><<<dim3(8, 8, 8), 256, 0, stream>>>(g, 256, 1024);

    reduce_4<<<1024, 256, 0, stream>>>((const unsigned short*)scr, (unsigned short*)Ytb);

    // L6: Ut = gemm_bt(Wv, Yt) (split-K4), 512 blocks
    for (int z = 0; z < 8; ++z) {
        const int h = z >> 2, s = z & 3;
        g.A[z] = wdst + (size_t)(4 + h) * M1 + s * 256;  g.lda[z] = 1024;
        g.B[z] = Ytb + (size_t)h * M1 + s * 256;         g.ldb[z] = 1024;
        g.C[z] = (bf16*)scr + (size_t)z * M1;
    }
    gemm_bt_pa<128, 128, bf16><<<dim3(8, 8, 8), 256, 0, stream>>>(g, 256, 1024);

    reduce_4<<<1024, 256, 0, stream>>>((const unsigned short*)scr, (unsigned short*)Utb);

    // O: O_h = gemm_bt(X_h, Ut_h) -> f32 out[:, h*1024:]  (128x64, 16 iters)
    for (int z = 0; z < 2; ++z) {
        g.A[z] = xb + (size_t)z * 1024;   g.lda[z] = 2048;
        g.B[z] = Utb + (size_t)z * M1;    g.ldb[z] = 1024;
        g.C[z] = (float*)d_out + (size_t)z * 1024;
    }
    gemm_bt_pa<128, 64, float><<<dim3(16, 32, 2), 256, 0, stream>>>(g, 1024, 2048);
}